// Round 11
// baseline (1042.983 us; speedup 1.0000x reference)
//
#include <hip/hip_runtime.h>

// LSTMNet: 2-layer LSTM (in=1, hid=32) + linear(32->1), B=2048, T=1024, fp32.
// R11 = R10 with the LAUNCH BUG fixed: block must be 512 threads (8 waves).
// R10 launched 256 -> all 4 waves took role 0 (wid>>2 == 0), no L1 wave ever
// ran, out[] stayed zero (absmax matched the R0 stub exactly).
// Design: LAYER-SPLIT wave specialization. Each batch row = TWO waves
// pipelined one step apart through a 2-slot LDS ring:
//   L0 wave (role 0): h0(t) = cell0(h0(t-1), x[t])      -- 32 weight regs
//   L1 wave (role 1): h1(s) = cell1(h0(s), h1(s-1)), s=t-1; head -> y[s]
//                                                        -- 64 weight regs
// Each wave's live set fits the 128-reg tier -> no AGPR parking, and
// 4096 waves = 4/SIMD (2 L0 + 2 L1) for latency hiding.
// Lane layout (proven R5-R9): 64 lanes = 32 units x 2 halves,
// half0 = gate rows j (i), 32+j (f); half1 = 64+j (g), 96+j (o).
// One __syncthreads per step; both role paths execute exactly TLEN barriers.

typedef _Float16 h2 __attribute__((ext_vector_type(2)));
typedef _Float16 h8 __attribute__((ext_vector_type(8)));

constexpr int BATCH = 2048;
constexpr int TLEN  = 1024;
constexpr int HID   = 32;
constexpr float L2E = 1.44269504088896f;   // log2(e)

union H8U { h8 v; h2 p[4]; };

static __device__ __forceinline__ float rcp_f(float v){ return __builtin_amdgcn_rcpf(v); }
static __device__ __forceinline__ float exp2_f(float v){ return __builtin_amdgcn_exp2f(v); }
static __device__ __forceinline__ float bcastf(float v, int k){
    return __int_as_float(__builtin_amdgcn_readlane(__float_as_int(v), k));
}
static __device__ __forceinline__ float dot2(h2 a, h2 b, float c){
    return __builtin_amdgcn_fdot2(a, b, c, false);   // v_dot2_f32_f16
}
static __device__ __forceinline__ int pki(float a, float b){
    h2 r; r.x = (_Float16)a; r.y = (_Float16)b;      // RNE converts
    return __builtin_bit_cast(int, r);
}
static __device__ __forceinline__ h2 asp(int v){ return __builtin_bit_cast(h2, v); }
static __device__ __forceinline__ float xchg32(float v, int xaddr){
    return __int_as_float(__builtin_amdgcn_ds_bpermute(xaddr, __float_as_int(v)));
}

__global__ void __launch_bounds__(512)
lstm2_v11(const float* __restrict__ x,
          const float* __restrict__ Wih0, const float* __restrict__ Whh0,
          const float* __restrict__ bih0, const float* __restrict__ bhh0,
          const float* __restrict__ Wih1, const float* __restrict__ Whh1,
          const float* __restrict__ bih1, const float* __restrict__ bhh1,
          const float* __restrict__ Wlin, const float* __restrict__ blin,
          float* __restrict__ out)
{
    const int tid  = threadIdx.x;
    const int lane = tid & 63;
    const int wid  = tid >> 6;                 // 0..7
    const int role = wid >> 2;                 // 0: layer-0 wave, 1: layer-1 wave
    const int rw   = wid & 3;                  // row within block
    const int b    = blockIdx.x * 4 + rw;      // batch row
    const int j    = lane & 31;
    const int hi   = lane >> 5;                // 0: i,f rows   1: g,o rows
    const int rowA = hi * 64 + j;              // i (hi=0) / g (hi=1)
    const int rowB = rowA + 32;                // f (hi=0) / o (hi=1)
    const int xaddr = (lane ^ 32) << 2;        // bpermute byte addr

    __shared__ alignas(16) _Float16 ring[2][4][32];     // h0 2-slot ring, [phase][row][unit]
    __shared__ alignas(16) _Float16 hstore[4][64][40];  // h1 per step, 80B stride
    __shared__ alignas(16) _Float16 wls[32];            // f16 Wlin copy

    // act-"a" selector: half0 -> sigmoid, half1 -> tanh (=2*sigm(2x)-1)
    const float kA = hi ? (-2.0f * L2E) : (-L2E);
    const float mA = hi ?  2.0f : 1.0f;
    const float cA = hi ? -1.0f : 0.0f;

    if (role == 0) {
        // ===================== layer-0 wave =====================
        int wA0i[16], wB0i[16];
        #pragma unroll
        for (int m = 0; m < 16; ++m){
            wA0i[m] = pki(Whh0[rowA * HID + 2*m], Whh0[rowA * HID + 2*m + 1]);
            wB0i[m] = pki(Whh0[rowB * HID + 2*m], Whh0[rowB * HID + 2*m + 1]);
        }
        float wa0 = Wih0[rowA];
        float wb0 = Wih0[rowB];
        float ba0 = bih0[rowA] + bhh0[rowA];
        float bb0 = bih0[rowB] + bhh0[rowB];

        H8U hp0[4];
        #pragma unroll
        for (int m = 0; m < 4; ++m) hp0[m].v = (h8)(_Float16)0.0f;
        float c0 = 0.0f;

        const float* xrow = x + (size_t)b * TLEN;
        float xchunk = 0.0f;

        for (int t = 0; t < TLEN; ++t){
            if ((t & 63) == 0) xchunk = xrow[t + lane];
            const float xt = bcastf(xchunk, t & 63);

            float ga  = __builtin_fmaf(wa0, xt, ba0);
            float gb  = __builtin_fmaf(wb0, xt, bb0);
            float ga2 = 0.0f, gb2 = 0.0f;
            #pragma unroll
            for (int m = 0; m < 4; ++m){
                ga  = dot2(asp(wA0i[4*m+0]), hp0[m].p[0], ga );
                gb  = dot2(asp(wB0i[4*m+0]), hp0[m].p[0], gb );
                ga2 = dot2(asp(wA0i[4*m+1]), hp0[m].p[1], ga2);
                gb2 = dot2(asp(wB0i[4*m+1]), hp0[m].p[1], gb2);
                ga  = dot2(asp(wA0i[4*m+2]), hp0[m].p[2], ga );
                gb  = dot2(asp(wB0i[4*m+2]), hp0[m].p[2], gb );
                ga2 = dot2(asp(wA0i[4*m+3]), hp0[m].p[3], ga2);
                gb2 = dot2(asp(wB0i[4*m+3]), hp0[m].p[3], gb2);
            }
            ga += ga2; gb += gb2;

            float act_a = __builtin_fmaf(mA, rcp_f(1.0f + exp2_f(ga * kA)), cA);
            float act_b = rcp_f(1.0f + exp2_f(gb * (-L2E)));
            const float oa = xchg32(act_a, xaddr);
            const float ob = xchg32(act_b, xaddr);
            const float fsel = hi ? ob : act_b;
            const float osel = hi ? act_b : ob;
            c0 = __builtin_fmaf(fsel, c0, act_a * oa);
            const float t0 = __builtin_fmaf(2.0f,
                    rcp_f(1.0f + exp2_f(c0 * (-2.0f * L2E))), -1.0f);
            const float h0 = osel * t0;

            ring[t & 1][rw][j] = (_Float16)h0;       // both halves write same value
            // read back transposed pairs for next step (own wave, in-order DS)
            {
                const h8* hv = (const h8*)&ring[t & 1][rw][0];
                #pragma unroll
                for (int m = 0; m < 4; ++m) hp0[m].v = hv[m];
            }
            __syncthreads();                          // publish h0(t) to L1 wave
        }
    } else {
        // ===================== layer-1 wave =====================
        int iA1i[16], iB1i[16], hA1i[16], hB1i[16];
        #pragma unroll
        for (int m = 0; m < 16; ++m){
            iA1i[m] = pki(Wih1[rowA * HID + 2*m], Wih1[rowA * HID + 2*m + 1]);
            iB1i[m] = pki(Wih1[rowB * HID + 2*m], Wih1[rowB * HID + 2*m + 1]);
            hA1i[m] = pki(Whh1[rowA * HID + 2*m], Whh1[rowA * HID + 2*m + 1]);
            hB1i[m] = pki(Whh1[rowB * HID + 2*m], Whh1[rowB * HID + 2*m + 1]);
        }
        float ba1 = bih1[rowA] + bhh1[rowA];
        float bb1 = bih1[rowB] + bhh1[rowB];
        const float bl = blin[0];
        wls[j] = (_Float16)Wlin[j];                  // all L1 waves write same values

        H8U hp1[4];
        #pragma unroll
        for (int m = 0; m < 4; ++m) hp1[m].v = (h8)(_Float16)0.0f;
        float c1 = 0.0f;

        float* orow = out + (size_t)b * TLEN;

        // one L1 step (s): consumes ring[s&1] (h0(s)), updates c1/hp1, stores y
        auto l1_step = [&](int s){
            H8U hp0r[4];
            {
                const h8* hv = (const h8*)&ring[s & 1][rw][0];
                #pragma unroll
                for (int m = 0; m < 4; ++m) hp0r[m].v = hv[m];
            }
            float pa = ba1, pb = bb1, pa2 = 0.0f, pb2 = 0.0f;
            float qa = 0.0f, qb = 0.0f, qa2 = 0.0f, qb2 = 0.0f;
            #pragma unroll
            for (int m = 0; m < 4; ++m){
                pa  = dot2(asp(iA1i[4*m+0]), hp0r[m].p[0], pa );
                pb  = dot2(asp(iB1i[4*m+0]), hp0r[m].p[0], pb );
                qa  = dot2(asp(hA1i[4*m+0]), hp1[m].p[0],  qa );
                qb  = dot2(asp(hB1i[4*m+0]), hp1[m].p[0],  qb );
                pa2 = dot2(asp(iA1i[4*m+1]), hp0r[m].p[1], pa2);
                pb2 = dot2(asp(iB1i[4*m+1]), hp0r[m].p[1], pb2);
                qa2 = dot2(asp(hA1i[4*m+1]), hp1[m].p[1],  qa2);
                qb2 = dot2(asp(hB1i[4*m+1]), hp1[m].p[1],  qb2);
                pa  = dot2(asp(iA1i[4*m+2]), hp0r[m].p[2], pa );
                pb  = dot2(asp(iB1i[4*m+2]), hp0r[m].p[2], pb );
                qa  = dot2(asp(hA1i[4*m+2]), hp1[m].p[2],  qa );
                qb  = dot2(asp(hB1i[4*m+2]), hp1[m].p[2],  qb );
                pa2 = dot2(asp(iA1i[4*m+3]), hp0r[m].p[3], pa2);
                pb2 = dot2(asp(iB1i[4*m+3]), hp0r[m].p[3], pb2);
                qa2 = dot2(asp(hA1i[4*m+3]), hp1[m].p[3],  qa2);
                qb2 = dot2(asp(hB1i[4*m+3]), hp1[m].p[3],  qb2);
            }
            const float g1a = (pa + pa2) + (qa + qa2);
            const float g1b = (pb + pb2) + (qb + qb2);

            float act_a1 = __builtin_fmaf(mA, rcp_f(1.0f + exp2_f(g1a * kA)), cA);
            float act_b1 = rcp_f(1.0f + exp2_f(g1b * (-L2E)));
            const float oa1 = xchg32(act_a1, xaddr);
            const float ob1 = xchg32(act_b1, xaddr);
            const float fsel = hi ? ob1 : act_b1;
            const float osel = hi ? act_b1 : ob1;
            c1 = __builtin_fmaf(fsel, c1, act_a1 * oa1);
            const float t1 = __builtin_fmaf(2.0f,
                    rcp_f(1.0f + exp2_f(c1 * (-2.0f * L2E))), -1.0f);
            const float h1 = osel * t1;

            hstore[rw][s & 63][j] = (_Float16)h1;    // per-step slot
            {
                const h8* hv = (const h8*)&hstore[rw][s & 63][0];
                #pragma unroll
                for (int m = 0; m < 4; ++m) hp1[m].v = hv[m];
            }
            if ((s & 63) == 63){
                // head for the whole chunk: lane t' -> y[t']
                H8U wl4[4], hr[4];
                const h8* wv = (const h8*)&wls[0];
                const h8* hv = (const h8*)&hstore[rw][lane][0];
                #pragma unroll
                for (int m = 0; m < 4; ++m){ wl4[m].v = wv[m]; hr[m].v = hv[m]; }
                float y = bl, y2 = 0.0f;
                #pragma unroll
                for (int m = 0; m < 4; ++m){
                    y  = dot2(wl4[m].p[0], hr[m].p[0], y );
                    y2 = dot2(wl4[m].p[1], hr[m].p[1], y2);
                    y  = dot2(wl4[m].p[2], hr[m].p[2], y );
                    y2 = dot2(wl4[m].p[3], hr[m].p[3], y2);
                }
                orow[(s - 63) + lane] = y + y2;       // coalesced store
            }
        };

        for (int t = 0; t < TLEN; ++t){
            if (t > 0) l1_step(t - 1);               // h0(t-1) published last iter
            __syncthreads();                          // matches L0's barrier at t
        }
        l1_step(TLEN - 1);                            // epilogue: last step, no barrier
    }
}

extern "C" void kernel_launch(void* const* d_in, const int* in_sizes, int n_in,
                              void* d_out, int out_size, void* d_ws, size_t ws_size,
                              hipStream_t stream) {
    const float* x    = (const float*)d_in[0];
    const float* Wih0 = (const float*)d_in[1];
    const float* Whh0 = (const float*)d_in[2];
    const float* bih0 = (const float*)d_in[3];
    const float* bhh0 = (const float*)d_in[4];
    const float* Wih1 = (const float*)d_in[5];
    const float* Whh1 = (const float*)d_in[6];
    const float* bih1 = (const float*)d_in[7];
    const float* bhh1 = (const float*)d_in[8];
    const float* Wlin = (const float*)d_in[9];
    const float* blin = (const float*)d_in[10];
    float* outp = (float*)d_out;

    dim3 block(512);                  // 8 waves: wid 0-3 = L0 rows 0-3, wid 4-7 = L1 rows 0-3
    dim3 grid(BATCH / 4);             // 512 blocks -> 4096 waves -> 4/SIMD
    hipLaunchKernelGGL(lstm2_v11, grid, block, 0, stream,
                       x, Wih0, Whh0, bih0, bhh0, Wih1, Whh1, bih1, bhh1,
                       Wlin, blin, outp);
}

// Round 12
// 702.727 us; speedup vs baseline: 1.4842x; 1.4842x over previous
//
#include <hip/hip_runtime.h>

// LSTMNet: 2-layer LSTM (in=1, hid=32) + linear(32->1), B=2048, T=1024, fp32.
// R12 = R9 structure (811us, passed) with the dot converted to the gfx950
// single-instruction bf16 dot (v_dot2_f32_bf16, f32 accumulate) when the
// builtin exists. Evidence: issue-rate fits 3.8 instr per weight-pair ->
// the f16 fdot2 builtin lowers to 2x v_fma_mix_f32 (gfx950 has no f16 VOP3P
// dot; R8's raw-asm attempt produced bf16-like garbage). A true 1-instr dot
// cuts ~190 of 755 issue-cyc/step. bf16 inputs + f32 accum: gate err ~1e-3,
// damped by the contractive recurrence -> absmax ~2 bf16 ulp, under 6.8e-3.
// #else keeps the proven f16 path (round degrades to an R7 re-bench).
// One wave per batch row; 64 lanes = 32 units x 2 halves (i,f | g,o).

typedef int i4 __attribute__((ext_vector_type(4)));

constexpr int BATCH = 2048;
constexpr int TLEN  = 1024;
constexpr int HID   = 32;
constexpr float L2E = 1.44269504088896f;   // log2(e)

#if __has_builtin(__builtin_amdgcn_fdot2_f32_bf16)
#define BF16_DOT 1
typedef __bf16 e2v __attribute__((ext_vector_type(2)));
static __device__ __forceinline__ float dot2i(int a, int b, float c){
    return __builtin_amdgcn_fdot2_f32_bf16(__builtin_bit_cast(e2v, a),
                                           __builtin_bit_cast(e2v, b), c, false);
}
static __device__ __forceinline__ unsigned cvt1(float f){   // RNE to bf16 bits
    unsigned u = __float_as_uint(f);
    return (u + 0x7FFFu + ((u >> 16) & 1u)) >> 16;
}
#else
#define BF16_DOT 0
typedef _Float16 e2v __attribute__((ext_vector_type(2)));
static __device__ __forceinline__ float dot2i(int a, int b, float c){
    return __builtin_amdgcn_fdot2(__builtin_bit_cast(e2v, a),
                                  __builtin_bit_cast(e2v, b), c, false);
}
static __device__ __forceinline__ unsigned cvt1(float f){   // f16 bits
    return (unsigned)__builtin_bit_cast(unsigned short, (_Float16)f);
}
#endif

static __device__ __forceinline__ int pk2(float a, float b){
    return (int)(cvt1(a) | (cvt1(b) << 16));   // low half = a, high half = b
}

union HP { i4 v; int q[4]; };

static __device__ __forceinline__ float rcp_f(float v){ return __builtin_amdgcn_rcpf(v); }
static __device__ __forceinline__ float exp2_f(float v){ return __builtin_amdgcn_exp2f(v); }
static __device__ __forceinline__ float bcastf(float v, int k){
    return __int_as_float(__builtin_amdgcn_readlane(__float_as_int(v), k));
}
static __device__ __forceinline__ float xchg32(float v, int xaddr){
    return __int_as_float(__builtin_amdgcn_ds_bpermute(xaddr, __float_as_int(v)));
}

__global__ void __launch_bounds__(256) __attribute__((amdgpu_waves_per_eu(2, 2)))
lstm2_v12(const float* __restrict__ x,
          const float* __restrict__ Wih0, const float* __restrict__ Whh0,
          const float* __restrict__ bih0, const float* __restrict__ bhh0,
          const float* __restrict__ Wih1, const float* __restrict__ Whh1,
          const float* __restrict__ bih1, const float* __restrict__ bhh1,
          const float* __restrict__ Wlin, const float* __restrict__ blin,
          float* __restrict__ out)
{
    const int tid  = threadIdx.x;
    const int lane = tid & 63;
    const int w    = tid >> 6;                 // wave within block (0..3)
    const int b    = blockIdx.x * 4 + w;       // batch row
    const int j    = lane & 31;
    const int hi   = lane >> 5;                // 0: i,f rows   1: g,o rows
    const int rowA = hi * 64 + j;              // i (hi=0) / g (hi=1)
    const int rowB = rowA + 32;                // f (hi=0) / o (hi=1)
    const int xaddr = (lane ^ 32) << 2;        // bpermute byte addr

    __shared__ alignas(16) unsigned short hb0s[4][32];        // h0 transpose buffer
    __shared__ alignas(16) unsigned short hstore[4][64][40];  // h1 per step, 80B stride
    __shared__ alignas(16) unsigned short wls[4][32];         // packed Wlin copy

    unsigned short* hb0p = &hb0s[w][0];

    // wave-local LDS init (both halves write identical values; no barriers)
    wls[w][j] = (unsigned short)cvt1(Wlin[j]);

    // ---- per-lane weights, packed pairs, PINNED in VGPRs ----
    int wA0i[16], wB0i[16], iA1i[16], iB1i[16], hA1i[16], hB1i[16];
    #pragma unroll
    for (int m = 0; m < 16; ++m){
        wA0i[m] = pk2(Whh0[rowA * HID + 2*m], Whh0[rowA * HID + 2*m + 1]);
        wB0i[m] = pk2(Whh0[rowB * HID + 2*m], Whh0[rowB * HID + 2*m + 1]);
        iA1i[m] = pk2(Wih1[rowA * HID + 2*m], Wih1[rowA * HID + 2*m + 1]);
        iB1i[m] = pk2(Wih1[rowB * HID + 2*m], Wih1[rowB * HID + 2*m + 1]);
        hA1i[m] = pk2(Whh1[rowA * HID + 2*m], Whh1[rowA * HID + 2*m + 1]);
        hB1i[m] = pk2(Whh1[rowB * HID + 2*m], Whh1[rowB * HID + 2*m + 1]);
    }
    #pragma unroll
    for (int m = 0; m < 16; ++m){
        asm volatile("" : "+v"(wA0i[m]), "+v"(wB0i[m]), "+v"(iA1i[m]),
                          "+v"(iB1i[m]), "+v"(hA1i[m]), "+v"(hB1i[m]));
    }

    float wa0 = Wih0[rowA];
    float wb0 = Wih0[rowB];
    float ba0 = bih0[rowA] + bhh0[rowA];
    float bb0 = bih0[rowB] + bhh0[rowB];
    float ba1 = bih1[rowA] + bhh1[rowA];
    float bb1 = bih1[rowB] + bhh1[rowB];
    float bl  = blin[0];
    asm volatile("" : "+v"(wa0), "+v"(wb0), "+v"(ba0), "+v"(bb0),
                      "+v"(ba1), "+v"(bb1), "+v"(bl));

    // act-"a" selector: half0 -> sigmoid, half1 -> tanh (=2*sigm(2x)-1)
    const float kA = hi ? (-2.0f * L2E) : (-L2E);
    const float mA = hi ?  2.0f : 1.0f;
    const float cA = hi ? -1.0f : 0.0f;

    float c0 = 0.0f, c1 = 0.0f;
    HP hp0[4], hp1[4];                         // h0/h1 as packed pairs (regs)
    #pragma unroll
    for (int m = 0; m < 4; ++m){
        hp0[m].v = (i4){0,0,0,0};
        hp1[m].v = (i4){0,0,0,0};
    }

    const float* xrow = x   + (size_t)b * TLEN;
    float*       orow = out + (size_t)b * TLEN;

    for (int tc = 0; tc < TLEN / 64; ++tc){
        const float xchunk = xrow[tc * 64 + lane];   // coalesced, 64 steps

        for (int tt = 0; tt < 64; ++tt){
            const float xt = bcastf(xchunk, tt);

            // ========= layer 0: g = Whh0*h0_prev + Wih0*x + b =========
            float ga  = __builtin_fmaf(wa0, xt, ba0);
            float gb  = __builtin_fmaf(wb0, xt, bb0);
            float ga2 = 0.0f, gb2 = 0.0f;
            #pragma unroll
            for (int m = 0; m < 4; ++m){
                ga  = dot2i(wA0i[4*m+0], hp0[m].q[0], ga );
                gb  = dot2i(wB0i[4*m+0], hp0[m].q[0], gb );
                ga2 = dot2i(wA0i[4*m+1], hp0[m].q[1], ga2);
                gb2 = dot2i(wB0i[4*m+1], hp0[m].q[1], gb2);
                ga  = dot2i(wA0i[4*m+2], hp0[m].q[2], ga );
                gb  = dot2i(wB0i[4*m+2], hp0[m].q[2], gb );
                ga2 = dot2i(wA0i[4*m+3], hp0[m].q[3], ga2);
                gb2 = dot2i(wB0i[4*m+3], hp0[m].q[3], gb2);
            }
            ga += ga2; gb += gb2;

            float act_a = __builtin_fmaf(mA, rcp_f(1.0f + exp2_f(ga * kA)), cA);
            float act_b = rcp_f(1.0f + exp2_f(gb * (-L2E)));
            const float oa = xchg32(act_a, xaddr);
            const float ob = xchg32(act_b, xaddr);
            {
                const float fsel = hi ? ob : act_b;
                const float osel = hi ? act_b : ob;
                c0 = __builtin_fmaf(fsel, c0, act_a * oa);
                const float t0 = __builtin_fmaf(2.0f,
                        rcp_f(1.0f + exp2_f(c0 * (-2.0f * L2E))), -1.0f);
                const float h0 = osel * t0;
                hb0p[j] = (unsigned short)cvt1(h0);  // ds_write_b16 (both halves same)
            }
            // read h0_new back as packed pairs (wave-uniform broadcast b128)
            {
                const i4* hv = (const i4*)hb0p;
                #pragma unroll
                for (int m = 0; m < 4; ++m) hp0[m].v = hv[m];
            }

            // ========= layer 1: g = Wih1*h0_new + Whh1*h1_prev + b =========
            float pa = ba1, pb = bb1, pa2 = 0.0f, pb2 = 0.0f;
            float qa = 0.0f, qb = 0.0f, qa2 = 0.0f, qb2 = 0.0f;
            #pragma unroll
            for (int m = 0; m < 4; ++m){
                pa  = dot2i(iA1i[4*m+0], hp0[m].q[0], pa );
                pb  = dot2i(iB1i[4*m+0], hp0[m].q[0], pb );
                qa  = dot2i(hA1i[4*m+0], hp1[m].q[0], qa );
                qb  = dot2i(hB1i[4*m+0], hp1[m].q[0], qb );
                pa2 = dot2i(iA1i[4*m+1], hp0[m].q[1], pa2);
                pb2 = dot2i(iB1i[4*m+1], hp0[m].q[1], pb2);
                qa2 = dot2i(hA1i[4*m+1], hp1[m].q[1], qa2);
                qb2 = dot2i(hB1i[4*m+1], hp1[m].q[1], qb2);
                pa  = dot2i(iA1i[4*m+2], hp0[m].q[2], pa );
                pb  = dot2i(iB1i[4*m+2], hp0[m].q[2], pb );
                qa  = dot2i(hA1i[4*m+2], hp1[m].q[2], qa );
                qb  = dot2i(hB1i[4*m+2], hp1[m].q[2], qb );
                pa2 = dot2i(iA1i[4*m+3], hp0[m].q[3], pa2);
                pb2 = dot2i(iB1i[4*m+3], hp0[m].q[3], pb2);
                qa2 = dot2i(hA1i[4*m+3], hp1[m].q[3], qa2);
                qb2 = dot2i(hB1i[4*m+3], hp1[m].q[3], qb2);
            }
            const float g1a = (pa + pa2) + (qa + qa2);
            const float g1b = (pb + pb2) + (qb + qb2);

            float act_a1 = __builtin_fmaf(mA, rcp_f(1.0f + exp2_f(g1a * kA)), cA);
            float act_b1 = rcp_f(1.0f + exp2_f(g1b * (-L2E)));
            const float oa1 = xchg32(act_a1, xaddr);
            const float ob1 = xchg32(act_b1, xaddr);
            {
                const float fsel = hi ? ob1 : act_b1;
                const float osel = hi ? act_b1 : ob1;
                c1 = __builtin_fmaf(fsel, c1, act_a1 * oa1);
                const float t1 = __builtin_fmaf(2.0f,
                        rcp_f(1.0f + exp2_f(c1 * (-2.0f * L2E))), -1.0f);
                const float h1 = osel * t1;
                hstore[w][tt][j] = (unsigned short)cvt1(h1);   // per-step slot
            }
            // read h1_new back (wave-uniform) for next step's recurrence
            {
                const i4* hv = (const i4*)&hstore[w][tt][0];
                #pragma unroll
                for (int m = 0; m < 4; ++m) hp1[m].v = hv[m];
            }
        }

        // ========= head for the whole chunk: lane t -> y[t] =========
        {
            HP wl4[4], hr[4];
            const i4* wv = (const i4*)&wls[w][0];
            const i4* hv = (const i4*)&hstore[w][lane][0];
            #pragma unroll
            for (int m = 0; m < 4; ++m){ wl4[m].v = wv[m]; hr[m].v = hv[m]; }
            float y = bl, y2 = 0.0f;
            #pragma unroll
            for (int m = 0; m < 4; ++m){
                y  = dot2i(wl4[m].q[0], hr[m].q[0], y );
                y2 = dot2i(wl4[m].q[1], hr[m].q[1], y2);
                y  = dot2i(wl4[m].q[2], hr[m].q[2], y );
                y2 = dot2i(wl4[m].q[3], hr[m].q[3], y2);
            }
            orow[tc * 64 + lane] = y + y2;           // coalesced store
        }
    }
}

extern "C" void kernel_launch(void* const* d_in, const int* in_sizes, int n_in,
                              void* d_out, int out_size, void* d_ws, size_t ws_size,
                              hipStream_t stream) {
    const float* x    = (const float*)d_in[0];
    const float* Wih0 = (const float*)d_in[1];
    const float* Whh0 = (const float*)d_in[2];
    const float* bih0 = (const float*)d_in[3];
    const float* bhh0 = (const float*)d_in[4];
    const float* Wih1 = (const float*)d_in[5];
    const float* Whh1 = (const float*)d_in[6];
    const float* bih1 = (const float*)d_in[7];
    const float* bhh1 = (const float*)d_in[8];
    const float* Wlin = (const float*)d_in[9];
    const float* blin = (const float*)d_in[10];
    float* outp = (float*)d_out;

    dim3 block(256);                 // 4 waves/block, 1 batch row per wave
    dim3 grid(BATCH / 4);            // 512 blocks -> 2048 waves -> 2/SIMD
    hipLaunchKernelGGL(lstm2_v12, grid, block, 0, stream,
                       x, Wih0, Whh0, bih0, bhh0, Wih1, Whh1, bih1, bhh1,
                       Wlin, blin, outp);
}